// Round 5
// baseline (351.986 us; speedup 1.0000x reference)
//
#include <hip/hip_runtime.h>

#define N_NODES 50000
#define N_PAD 50176                       // padded node space (RNODES*4)
#define N_EDGES 800000
#define NCHUNK 128
#define NRANGE 4
#define RNODES 12544                      // N_PAD / NRANGE
#define CEDGES (N_EDGES / NCHUNK)         // 6250
#define HIST_NB (NCHUNK * NRANGE)         // 512
#define SCAN_NB 782                       // 64-node scan blocks
#define GATB 12500                        // gather blocks per plane (4 nodes each)
#define NBLK 782                          // 64-row GEMM tiles
#define PLANE ((long)N_PAD * 32)          // elems per feature plane

typedef __attribute__((ext_vector_type(8))) short short8;
typedef __attribute__((ext_vector_type(4))) float f32x4;

struct LPtrs { const float *W1, *W2, *W3, *Wl, *b1, *b3, *bl; };
struct AllPtrs { LPtrs l[3]; };

__device__ inline unsigned short f2b(float f) {
    union { float f; unsigned u; } c; c.f = f;
    return (unsigned short)((c.u + 0x7FFFu + ((c.u >> 16) & 1u)) >> 16);
}
__device__ inline float b2f(unsigned short h) {
    union { unsigned u; float f; } c; c.u = ((unsigned)h) << 16;
    return c.f;
}

// ---------------------------------------------------------------------------
// K1 (fused): blocks 0..511 partial histograms (packed-u8 LDS atomics);
// blocks 512..547 pack Wml = Wm@Wl bf16 tiles + bias rows;
// blocks 548..1329 cast x (f32) -> h0 (bf16, plane-split layout).
__global__ __launch_bounds__(256) void histcast_kernel(
    const int* __restrict__ dst, unsigned char* __restrict__ hist_part,
    AllPtrs ap, unsigned short* __restrict__ Wp, float* __restrict__ rows,
    const float* __restrict__ x, unsigned short* __restrict__ h0)
{
    __shared__ unsigned int h[5248];          // 21 KB; hist uses 3136 words
    const int t = threadIdx.x;
    if (blockIdx.x < HIST_NB) {
        const int chunk = blockIdx.x >> 2;
        const int range = blockIdx.x & 3;
        const int nbase = range * RNODES;
        for (int i = t; i < RNODES / 4; i += 256) h[i] = 0u;
        __syncthreads();
        const int* dp = dst + chunk * CEDGES;
        for (int i = t; i < CEDGES; i += 256) {
            int d = dp[i] - nbase;
            if ((unsigned)d < (unsigned)RNODES)
                atomicAdd(&h[d >> 2], 1u << ((d & 3) * 8));
        }
        __syncthreads();
        unsigned int* out = (unsigned int*)(hist_part + (long)chunk * N_PAD + nbase);
        for (int i = t; i < RNODES / 4; i += 256) out[i] = h[i];
    } else if (blockIdx.x < HIST_NB + 36) {
        float* sW = (float*)h;                // 64x65
        float* sL = (float*)h + 64 * 65;      // 64x17
        const int wi = blockIdx.x - HIST_NB;
        const int layer = wi / 12;
        const int ct = wi % 12;
        LPtrs L = ap.l[layer];
        const float* Wm = (ct < 4) ? L.W1 : (ct < 8) ? L.W2 : L.W3;
        const int colb = (ct & 3) * 16;
        for (int i = t; i < 64 * 64; i += 256) sW[(i >> 6) * 65 + (i & 63)] = Wm[i];
        for (int i = t; i < 64 * 16; i += 256) {
            int q = i >> 4, c = i & 15;
            sL[q * 17 + c] = L.Wl[q * 64 + colb + c];
        }
        __syncthreads();
        for (int local = t; local < 1024; local += 256) {
            int j = local & 7, lane = (local >> 3) & 63, s = local >> 9;
            int k = s * 32 + (lane >> 4) * 8 + j;
            int c = lane & 15;
            float acc = 0.f;
            #pragma unroll 8
            for (int q = 0; q < 64; ++q) acc += sW[k * 65 + q] * sL[q * 17 + c];
            Wp[layer * 12288 + ct * 1024 + local] = f2b(acc);
        }
        if (ct == 0 && t < 64) {
            int col = t;
            float r1 = 0.f, r3 = 0.f;
            for (int q = 0; q < 64; ++q) {
                float wl = L.Wl[q * 64 + col];
                r1 += L.b1[q] * wl;
                r3 += L.b3[q] * wl;
            }
            rows[layer * 128 + col] = r1;
            rows[layer * 128 + 64 + col] = r3 + L.bl[col];
        }
    } else {
        const int cb = blockIdx.x - HIST_NB - 36;
        const long base = (long)cb * 4096 + t * 16;
        if (base < (long)N_NODES * 64) {
            const int row = (int)(base >> 6);
            const int e0 = (int)(base & 63);      // 0,16,32,48
            const float4* xp = (const float4*)(x + base);
            float4 f0 = xp[0], f1 = xp[1], f2 = xp[2], f3 = xp[3];
            short8 r0, r1v;
            r0[0] = (short)f2b(f0.x); r0[1] = (short)f2b(f0.y);
            r0[2] = (short)f2b(f0.z); r0[3] = (short)f2b(f0.w);
            r0[4] = (short)f2b(f1.x); r0[5] = (short)f2b(f1.y);
            r0[6] = (short)f2b(f1.z); r0[7] = (short)f2b(f1.w);
            r1v[0] = (short)f2b(f2.x); r1v[1] = (short)f2b(f2.y);
            r1v[2] = (short)f2b(f2.z); r1v[3] = (short)f2b(f2.w);
            r1v[4] = (short)f2b(f3.x); r1v[5] = (short)f2b(f3.y);
            r1v[6] = (short)f2b(f3.z); r1v[7] = (short)f2b(f3.w);
            unsigned short* dp2 = h0 + (e0 >> 5) * PLANE + (long)row * 32 + (e0 & 31);
            *(short8*)dp2 = r0;
            *(short8*)(dp2 + 8) = r1v;
        }
    }
}

// ---------------------------------------------------------------------------
// K2: per-node exclusive scan across 128 chunks, 4 threads/node.
__global__ __launch_bounds__(256) void scanA2_kernel(unsigned char* __restrict__ hist_part,
                                                     int* __restrict__ off,
                                                     int* __restrict__ deg,
                                                     int* __restrict__ bsum) {
    __shared__ int part[4][64];
    const int t = threadIdx.x;
    const int ln = t & 63;
    const int cg = t >> 6;
    const int node = blockIdx.x * 64 + ln;
    unsigned char* col = hist_part + node;
    unsigned char v[32];
    int s = 0;
    #pragma unroll
    for (int k = 0; k < 32; ++k) {
        v[k] = col[(long)(cg * 32 + k) * N_PAD];
        s += v[k];
    }
    part[cg][ln] = s;
    __syncthreads();
    int run = 0, tot = 0;
    #pragma unroll
    for (int g = 0; g < 4; ++g) {
        int p = part[g][ln];
        if (g < cg) run += p;
        tot += p;
    }
    #pragma unroll
    for (int k = 0; k < 32; ++k) {
        col[(long)(cg * 32 + k) * N_PAD] = (unsigned char)run;
        run += v[k];
    }
    if (cg == 0) {
        deg[node] = tot;
        int xv = tot;
        #pragma unroll
        for (int d = 1; d < 64; d <<= 1) {
            int u = __shfl_up(xv, d, 64);
            if (ln >= d) xv += u;
        }
        off[node] = xv - tot;
        if (ln == 63) bsum[blockIdx.x] = xv;
    }
}

// ---------------------------------------------------------------------------
// gemm_w body: w = h@W3l - deg*((h@W2l) - row1) + row3 (tiles 4..11 of Wp).
// h read from plane-split layout.
__device__ __forceinline__ void gemmw_body(int blk, int t,
    const unsigned short* __restrict__ hpl, const unsigned short* __restrict__ Wp,
    const int* __restrict__ deg, const float* __restrict__ rows,
    unsigned short* __restrict__ wbf, int n)
{
    const int lane = t & 63;
    const int quad = lane >> 4, lm = lane & 15;
    const int row_base = blk * 64 + (t >> 6) * 16;

    int arow = min(row_base + lm, n - 1);
    short8 a0 = *(const short8*)(hpl + (long)arow * 32 + quad * 8);
    short8 a1 = *(const short8*)(hpl + PLANE + (long)arow * 32 + quad * 8);

    const short8* wp = (const short8*)Wp;
    f32x4 acc[8];
    #pragma unroll
    for (int ct = 0; ct < 8; ++ct) {
        int tile = ct + 4;
        f32x4 z = {0.f, 0.f, 0.f, 0.f};
        short8 w0 = wp[(tile * 2 + 0) * 64 + lane];
        short8 w1 = wp[(tile * 2 + 1) * 64 + lane];
        z = __builtin_amdgcn_mfma_f32_16x16x32_bf16(a0, w0, z, 0, 0, 0);
        z = __builtin_amdgcn_mfma_f32_16x16x32_bf16(a1, w1, z, 0, 0, 0);
        acc[ct] = z;
    }

    const int g0 = row_base + quad * 4;
    float dg[4];
    #pragma unroll
    for (int r = 0; r < 4; ++r) dg[r] = (float)deg[min(g0 + r, n - 1)];

    #pragma unroll
    for (int ct = 0; ct < 4; ++ct) {
        int col = ct * 16 + lm;
        float r1 = rows[col];
        float r3 = rows[64 + col];
        #pragma unroll
        for (int r = 0; r < 4; ++r) {
            int g = g0 + r;
            if (g < n) {
                float wv = acc[4 + ct][r] - dg[r] * (acc[ct][r] - r1) + r3;
                wbf[(long)g * 64 + col] = f2b(wv);
            }
        }
    }
}

// ---------------------------------------------------------------------------
// K3 (fused): blocks 0..511 fill csr (bsum scan folded in; block 0 publishes
// boff; chunk==0 blocks also publish rowinfo = {abs beg, deg});
// blocks 512..1293 compute layer-0 w concurrently.
__global__ __launch_bounds__(256) void fillw_kernel(
    const int* __restrict__ src, const int* __restrict__ dst,
    const int* __restrict__ off, const int* __restrict__ bsum,
    int* __restrict__ boff, const unsigned char* __restrict__ hist_part,
    int* __restrict__ csr, int2* __restrict__ rowinfo,
    const unsigned short* __restrict__ h0, const unsigned short* __restrict__ Wp,
    const int* __restrict__ deg, const float* __restrict__ rows,
    unsigned short* __restrict__ wbf)
{
    __shared__ int cur[RNODES];               // 50 KB
    __shared__ int sb[1024];
    if (blockIdx.x >= HIST_NB) {
        gemmw_body(blockIdx.x - HIST_NB, threadIdx.x, h0, Wp, deg, rows,
                   wbf, N_NODES);
        return;
    }
    const int t = threadIdx.x;

    const int i0 = t * 4;
    int a0 = (i0 + 0 < SCAN_NB) ? bsum[i0 + 0] : 0;
    int a1 = (i0 + 1 < SCAN_NB) ? bsum[i0 + 1] : 0;
    int a2 = (i0 + 2 < SCAN_NB) ? bsum[i0 + 2] : 0;
    int a3 = (i0 + 3 < SCAN_NB) ? bsum[i0 + 3] : 0;
    int s = a0 + a1 + a2 + a3;
    cur[t] = s;
    __syncthreads();
    #pragma unroll
    for (int d = 1; d < 256; d <<= 1) {
        int u = (t >= d) ? cur[t - d] : 0;
        __syncthreads();
        cur[t] += u;
        __syncthreads();
    }
    int excl = cur[t] - s;
    sb[i0 + 0] = excl;
    sb[i0 + 1] = excl + a0;
    sb[i0 + 2] = excl + a0 + a1;
    sb[i0 + 3] = excl + a0 + a1 + a2;
    __syncthreads();
    if (blockIdx.x == 0)
        for (int i = t; i < SCAN_NB; i += 256) boff[i] = sb[i];

    const int chunk = blockIdx.x >> 2;
    const int range = blockIdx.x & 3;
    const int nbase = range * RNODES;
    const unsigned char* bp = hist_part + (long)chunk * N_PAD + nbase;
    const int* op = off + nbase;
    const int lim = min(RNODES, N_NODES - nbase);
    for (int i = t; i < lim; i += 256) {
        int c = op[i] + sb[(nbase + i) >> 6] + (int)bp[i];
        cur[i] = c;
        if (chunk == 0)                       // bp==0 here: c = absolute row beg
            rowinfo[nbase + i] = make_int2(c, deg[nbase + i]);
    }
    __syncthreads();
    const int* dp = dst + chunk * CEDGES;
    const int* sp = src + chunk * CEDGES;
    for (int i = t; i < CEDGES; i += 256) {
        int d = dp[i] - nbase;
        if ((unsigned)d < (unsigned)RNODES) {
            int pos = atomicAdd(&cur[d], 1);
            csr[pos] = sp[i];
        }
    }
}

// ---------------------------------------------------------------------------
// K4 (fused): blocks 0..gw-1 run gemm_w; then 2*GATB gather blocks, plane 0
// first then plane 1 — each plane's random reads hit a 3.2 MB table that
// fits in a per-XCD L2. Wave = node; 8-lane groups = 8 edges in flight.
__global__ __launch_bounds__(256) void gatherw_kernel(
    const int2* __restrict__ rowinfo, const int* __restrict__ csr,
    const unsigned short* __restrict__ hpl, unsigned short* __restrict__ Spl,
    const unsigned short* __restrict__ Wp, const int* __restrict__ degv,
    const float* __restrict__ rows, unsigned short* __restrict__ wbf, int gw)
{
    if (blockIdx.x < gw) {
        gemmw_body(blockIdx.x, threadIdx.x, hpl, Wp, degv, rows, wbf, N_NODES);
        return;
    }
    int pb = blockIdx.x - gw;
    int plane = 0;
    if (pb >= GATB) { plane = 1; pb -= GATB; }
    const int node = pb * 4 + (threadIdx.x >> 6);
    const int lane = threadIdx.x & 63;
    const int g = lane >> 3;                  // edge slot 0..7
    const int f = (lane & 7) * 4;             // feature quad within plane
    const unsigned short* hp = hpl + plane * PLANE;

    int2 ri = rowinfo[node];
    const int beg = ri.x, dgn = ri.y;
    float ax = 0.f, ay = 0.f, az = 0.f, aw = 0.f;
    int j = beg + g;
    const int nfull = dgn >> 3;
    for (int k = 0; k < nfull; ++k, j += 8) {
        int s = csr[j];
        ushort4 v = *(const ushort4*)(hp + (long)s * 32 + f);
        ax += b2f(v.x); ay += b2f(v.y); az += b2f(v.z); aw += b2f(v.w);
    }
    if (j < beg + dgn) {
        int s = csr[j];
        ushort4 v = *(const ushort4*)(hp + (long)s * 32 + f);
        ax += b2f(v.x); ay += b2f(v.y); az += b2f(v.z); aw += b2f(v.w);
    }
    #pragma unroll
    for (int m = 8; m < 64; m <<= 1) {
        ax += __shfl_xor(ax, m, 64);
        ay += __shfl_xor(ay, m, 64);
        az += __shfl_xor(az, m, 64);
        aw += __shfl_xor(aw, m, 64);
    }
    if (g == 0) {
        ushort4 o;
        o.x = f2b(ax); o.y = f2b(ay); o.z = f2b(az); o.w = f2b(aw);
        *(ushort4*)(Spl + plane * PLANE + (long)node * 32 + f) = o;
    }
}

// ---------------------------------------------------------------------------
// K5: out = relu(S@W1l + w) (tiles 0..3 of Wp); h_next in plane layout.
__global__ __launch_bounds__(256) void out_kernel(
    const unsigned short* __restrict__ Spl, const unsigned short* __restrict__ wbf,
    const unsigned short* __restrict__ Wp,
    unsigned short* __restrict__ houtpl, float* __restrict__ fout, int last, int n)
{
    const int t = threadIdx.x;
    const int lane = t & 63;
    const int quad = lane >> 4, lm = lane & 15;
    const int row_base = blockIdx.x * 64 + (t >> 6) * 16;

    int arow = min(row_base + lm, n - 1);
    short8 a0 = *(const short8*)(Spl + (long)arow * 32 + quad * 8);
    short8 a1 = *(const short8*)(Spl + PLANE + (long)arow * 32 + quad * 8);

    const short8* wp = (const short8*)Wp;
    f32x4 acc[4];
    #pragma unroll
    for (int ct = 0; ct < 4; ++ct) {
        f32x4 z = {0.f, 0.f, 0.f, 0.f};
        short8 w0 = wp[(ct * 2 + 0) * 64 + lane];
        short8 w1 = wp[(ct * 2 + 1) * 64 + lane];
        z = __builtin_amdgcn_mfma_f32_16x16x32_bf16(a0, w0, z, 0, 0, 0);
        z = __builtin_amdgcn_mfma_f32_16x16x32_bf16(a1, w1, z, 0, 0, 0);
        acc[ct] = z;
    }

    const int g0 = row_base + quad * 4;
    #pragma unroll
    for (int ct = 0; ct < 4; ++ct) {
        int col = ct * 16 + lm;
        #pragma unroll
        for (int r = 0; r < 4; ++r) {
            int g = g0 + r;
            if (g < n) {
                float val = acc[ct][r] + b2f(wbf[(long)g * 64 + col]);
                val = fmaxf(val, 0.f);
                if (last) fout[(long)g * 64 + col] = val;
                else      houtpl[(col >> 5) * PLANE + (long)g * 32 + (col & 31)] = f2b(val);
            }
        }
    }
}

// ---------------------------------------------------------------------------
extern "C" void kernel_launch(void* const* d_in, const int* in_sizes, int n_in,
                              void* d_out, int out_size, void* d_ws, size_t ws_size,
                              hipStream_t stream) {
    const float* x  = (const float*)d_in[0];
    const int*   ei = (const int*)d_in[1];
    const int*   src = ei;
    const int*   dst = ei + N_EDGES;

    char* wsb = (char*)d_ws;
    unsigned char*  hist_part = (unsigned char*)(wsb);          // 6.42 MB
    unsigned short* h0   = (unsigned short*)(wsb + 6500000);    // 2 planes, 6.42 MB
    unsigned short* h1   = (unsigned short*)(wsb + 12950000);   // 2 planes
    unsigned short* Spl  = (unsigned short*)(wsb + 19400000);   // 2 planes
    unsigned short* wbf  = (unsigned short*)(wsb + 25850000);   // 6.42 MB
    unsigned short* Wp   = (unsigned short*)(wsb + 32300000);   // 72 KB
    float*          rows = (float*)(wsb + 32400000);            // 1.5 KB
    int*  deg     = (int*)(wsb + 32500000);                     // N_PAD
    int*  off     = (int*)(wsb + 32750000);                     // N_PAD
    int*  bsum    = (int*)(wsb + 33000000);                     // 1024
    int*  boff    = (int*)(wsb + 33010000);                     // 1024
    int2* rowinfo = (int2*)(wsb + 33020000);                    // N_PAD int2
    int*  csr     = (int*)(wsb + 33450000);                     // N_EDGES

    AllPtrs ap;
    for (int l = 0; l < 3; ++l) {
        int base = 2 + l * 7;
        ap.l[l].W1 = (const float*)d_in[base + 0];
        ap.l[l].b1 = (const float*)d_in[base + 1];
        ap.l[l].W2 = (const float*)d_in[base + 2];
        ap.l[l].W3 = (const float*)d_in[base + 3];
        ap.l[l].b3 = (const float*)d_in[base + 4];
        ap.l[l].Wl = (const float*)d_in[base + 5];
        ap.l[l].bl = (const float*)d_in[base + 6];
    }

    // ---- CSR build + pack + x-cast; layer-0 w overlaps the fill ----
    histcast_kernel<<<HIST_NB + 36 + 782, 256, 0, stream>>>(
        dst, hist_part, ap, Wp, rows, x, h0);
    scanA2_kernel<<<SCAN_NB, 256, 0, stream>>>(hist_part, off, deg, bsum);
    fillw_kernel<<<HIST_NB + NBLK, 256, 0, stream>>>(
        src, dst, off, bsum, boff, hist_part, csr, rowinfo,
        h0, Wp, deg, rows, wbf);

    // layer 0: gather (w done above), then out -> h1
    gatherw_kernel<<<2 * GATB, 256, 0, stream>>>(
        rowinfo, csr, h0, Spl, Wp, deg, rows, wbf, 0);
    out_kernel<<<NBLK, 256, 0, stream>>>(Spl, wbf, Wp, h1, nullptr, 0, N_NODES);

    // layer 1: gemm_w ∥ gather on h1, then out -> h0
    gatherw_kernel<<<NBLK + 2 * GATB, 256, 0, stream>>>(
        rowinfo, csr, h1, Spl, Wp + 12288, deg, rows + 128, wbf, NBLK);
    out_kernel<<<NBLK, 256, 0, stream>>>(Spl, wbf, Wp + 12288, h0, nullptr, 0, N_NODES);

    // layer 2: gemm_w ∥ gather on h0, then out -> d_out (f32)
    gatherw_kernel<<<NBLK + 2 * GATB, 256, 0, stream>>>(
        rowinfo, csr, h0, Spl, Wp + 24576, deg, rows + 256, wbf, NBLK);
    out_kernel<<<NBLK, 256, 0, stream>>>(Spl, wbf, Wp + 24576, nullptr,
                                         (float*)d_out, 1, N_NODES);
}

// Round 6
// 268.928 us; speedup vs baseline: 1.3088x; 1.3088x over previous
//
#include <hip/hip_runtime.h>

#define N_NODES 50000
#define N_EDGES 800000
#define NCHUNK 128
#define NRANGE 4
#define RNODES (N_NODES / NRANGE)         // 12500
#define CEDGES (N_EDGES / NCHUNK)         // 6250
#define HIST_NB (NCHUNK * NRANGE)         // 512
#define SCAN_NB 782                       // 64-node scan blocks (50048 >= N_NODES)
#define NBLK 782                          // 64-row GEMM tiles

typedef __attribute__((ext_vector_type(8))) short short8;
typedef __attribute__((ext_vector_type(4))) float f32x4;

struct LPtrs { const float *W1, *W2, *W3, *Wl, *b1, *b3, *bl; };
struct AllPtrs { LPtrs l[3]; };

__device__ inline unsigned short f2b(float f) {
    union { float f; unsigned u; } c; c.f = f;
    return (unsigned short)((c.u + 0x7FFFu + ((c.u >> 16) & 1u)) >> 16);
}
__device__ inline float b2f(unsigned short h) {
    union { unsigned u; float f; } c; c.u = ((unsigned)h) << 16;
    return c.f;
}

// ---------------------------------------------------------------------------
// K1 (fused): blocks 0..511 build partial histograms (packed-u8 LDS atomics:
// 4 counters/word, per-(chunk,node) count <= ~8, no overflow); blocks
// 512..547 pack Wml = Wm@Wl into B-frag bf16 + bias rows.
__global__ __launch_bounds__(256) void histpack_kernel(const int* __restrict__ dst,
                                                       unsigned char* __restrict__ hist_part,
                                                       AllPtrs ap,
                                                       unsigned short* __restrict__ Wp,
                                                       float* __restrict__ rows) {
    __shared__ unsigned int h[5248];          // 21 KB; hist path uses 3125 words
    const int t = threadIdx.x;
    if (blockIdx.x < HIST_NB) {
        const int chunk = blockIdx.x >> 2;
        const int range = blockIdx.x & 3;
        const int nbase = range * RNODES;
        for (int i = t; i < RNODES / 4; i += 256) h[i] = 0u;
        __syncthreads();
        const int* dp = dst + chunk * CEDGES;
        for (int i = t; i < CEDGES; i += 256) {
            int d = dp[i] - nbase;
            if ((unsigned)d < (unsigned)RNODES)
                atomicAdd(&h[d >> 2], 1u << ((d & 3) * 8));
        }
        __syncthreads();
        unsigned int* out = (unsigned int*)(hist_part + (long)chunk * N_NODES + nbase);
        for (int i = t; i < RNODES / 4; i += 256) out[i] = h[i];
    } else {
        float* sW = (float*)h;                // 64x65
        float* sL = (float*)h + 64 * 65;      // 64x17 (21 KB total)
        const int wi = blockIdx.x - HIST_NB;
        const int layer = wi / 12;
        const int ct = wi % 12;
        LPtrs L = ap.l[layer];
        const float* Wm = (ct < 4) ? L.W1 : (ct < 8) ? L.W2 : L.W3;
        const int colb = (ct & 3) * 16;
        for (int i = t; i < 64 * 64; i += 256) sW[(i >> 6) * 65 + (i & 63)] = Wm[i];
        for (int i = t; i < 64 * 16; i += 256) {
            int q = i >> 4, c = i & 15;
            sL[q * 17 + c] = L.Wl[q * 64 + colb + c];
        }
        __syncthreads();
        for (int local = t; local < 1024; local += 256) {
            int j = local & 7, lane = (local >> 3) & 63, s = local >> 9;
            int k = s * 32 + (lane >> 4) * 8 + j;
            int c = lane & 15;
            float acc = 0.f;
            #pragma unroll 8
            for (int q = 0; q < 64; ++q) acc += sW[k * 65 + q] * sL[q * 17 + c];
            Wp[layer * 12288 + ct * 1024 + local] = f2b(acc);
        }
        if (ct == 0 && t < 64) {
            int col = t;
            float r1 = 0.f, r3 = 0.f;
            for (int q = 0; q < 64; ++q) {
                float wl = L.Wl[q * 64 + col];
                r1 += L.b1[q] * wl;
                r3 += L.b3[q] * wl;
            }
            rows[layer * 128 + col] = r1;
            rows[layer * 128 + 64 + col] = r3 + L.bl[col];
        }
    }
}

// ---------------------------------------------------------------------------
// K2: per-node exclusive scan across 128 chunks, 4 threads/node (32
// independent u8 loads each — fully pipelined; replaces the serial 128-chain
// at 1 wave/SIMD). 64 nodes/block, 782 blocks. Wave 0 shuffle-scans the 64
// node totals -> off (block-partial) + bsum.
__global__ __launch_bounds__(256) void scanA2_kernel(unsigned char* __restrict__ hist_part,
                                                     int* __restrict__ off,
                                                     int* __restrict__ deg,
                                                     int* __restrict__ bsum) {
    __shared__ int part[4][64];
    const int t = threadIdx.x;
    const int ln = t & 63;
    const int cg = t >> 6;                    // chunk group: 32 chunks each
    const int node = blockIdx.x * 64 + ln;
    unsigned char* col = hist_part + node;
    unsigned char v[32];
    int s = 0;
    if (node < N_NODES) {
        #pragma unroll
        for (int k = 0; k < 32; ++k) {
            v[k] = col[(long)(cg * 32 + k) * N_NODES];
            s += v[k];
        }
    }
    part[cg][ln] = s;
    __syncthreads();
    int run = 0, tot = 0;
    #pragma unroll
    for (int g = 0; g < 4; ++g) {
        int p = part[g][ln];
        if (g < cg) run += p;
        tot += p;
    }
    if (node < N_NODES) {
        #pragma unroll
        for (int k = 0; k < 32; ++k) {
            col[(long)(cg * 32 + k) * N_NODES] = (unsigned char)run;
            run += v[k];
        }
    }
    if (cg == 0) {
        if (node < N_NODES) deg[node] = tot;
        int x = tot;
        #pragma unroll
        for (int d = 1; d < 64; d <<= 1) {
            int u = __shfl_up(x, d, 64);
            if (ln >= d) x += u;
        }
        if (node < N_NODES) off[node] = x - tot;
        if (ln == 63) bsum[blockIdx.x] = x;
    }
}

// ---------------------------------------------------------------------------
// gemm core: a' = h@W1l; w = (h@W3l) - deg*((h@W2l) - row1) + row3, one pass.
// bf16 MFMA, no LDS. hf32 != null (layer 0): read fp32 x, cast in-register.
__device__ __forceinline__ void gemm_body(int blk, int t,
    const unsigned short* __restrict__ hbf, const float* __restrict__ hf32,
    const unsigned short* __restrict__ Wp,
    const int* __restrict__ deg, const float* __restrict__ rows,
    unsigned short* __restrict__ abf, unsigned short* __restrict__ wbf, int n)
{
    const int lane = t & 63;
    const int quad = lane >> 4, lm = lane & 15;
    const int row_base = blk * 64 + (t >> 6) * 16;

    int arow = min(row_base + lm, n - 1);
    short8 a0, a1;
    if (hf32) {
        const float* hrow = hf32 + (long)arow * 64;
        #pragma unroll
        for (int j = 0; j < 8; ++j) {
            a0[j] = (short)f2b(hrow[quad * 8 + j]);
            a1[j] = (short)f2b(hrow[32 + quad * 8 + j]);
        }
    } else {
        const unsigned short* hrow = hbf + (long)arow * 64;
        a0 = *(const short8*)(hrow + quad * 8);
        a1 = *(const short8*)(hrow + 32 + quad * 8);
    }

    const short8* wp = (const short8*)Wp;
    f32x4 acc[12];
    #pragma unroll
    for (int ct = 0; ct < 12; ++ct) {
        f32x4 z = {0.f, 0.f, 0.f, 0.f};
        short8 w0 = wp[(ct * 2 + 0) * 64 + lane];
        short8 w1 = wp[(ct * 2 + 1) * 64 + lane];
        z = __builtin_amdgcn_mfma_f32_16x16x32_bf16(a0, w0, z, 0, 0, 0);
        z = __builtin_amdgcn_mfma_f32_16x16x32_bf16(a1, w1, z, 0, 0, 0);
        acc[ct] = z;
    }

    const int g0 = row_base + quad * 4;
    float dg[4];
    #pragma unroll
    for (int r = 0; r < 4; ++r) dg[r] = (float)deg[min(g0 + r, n - 1)];

    #pragma unroll
    for (int ct = 0; ct < 4; ++ct) {
        int col = ct * 16 + lm;
        float r1 = rows[col];
        float r3 = rows[64 + col];
        #pragma unroll
        for (int r = 0; r < 4; ++r) {
            int g = g0 + r;
            if (g < n) {
                abf[(long)g * 64 + col] = f2b(acc[ct][r]);
                float wv = acc[8 + ct][r] - dg[r] * (acc[4 + ct][r] - r1) + r3;
                wbf[(long)g * 64 + col] = f2b(wv);
            }
        }
    }
}

__global__ __launch_bounds__(256) void gemm3w_kernel(
    const unsigned short* __restrict__ hbf, const float* __restrict__ hf32,
    const unsigned short* __restrict__ Wp,
    const int* __restrict__ deg, const float* __restrict__ rows,
    unsigned short* __restrict__ abf, unsigned short* __restrict__ wbf, int n)
{
    gemm_body(blockIdx.x, threadIdx.x, hbf, hf32, Wp, deg, rows, abf, wbf, n);
}

// ---------------------------------------------------------------------------
// K3 (fused): blocks 0..511 fill csr (bsum[782] scan folded in: 4 contiguous
// sums/thread + one 256-scan; chunk-0 blocks publish rowinfo = {abs beg,
// deg}); blocks 512..1293 run the layer-0 GEMM concurrently (fill blocks
// dispatch first, so the fill critical path keeps all CU slots).
__global__ __launch_bounds__(256) void fillgemm_kernel(
    const int* __restrict__ src, const int* __restrict__ dst,
    const int* __restrict__ off, const int* __restrict__ bsum,
    const unsigned char* __restrict__ hist_part,
    int* __restrict__ csr, int2* __restrict__ rowinfo,
    const float* __restrict__ x, const unsigned short* __restrict__ Wp,
    const int* __restrict__ deg, const float* __restrict__ rows,
    unsigned short* __restrict__ abf, unsigned short* __restrict__ wbf)
{
    __shared__ int cur[RNODES];               // 50 KB (scan reuses first 256)
    __shared__ int sb[1024];                  // 4 KB scanned block sums
    if (blockIdx.x >= HIST_NB) {
        gemm_body(blockIdx.x - HIST_NB, threadIdx.x, nullptr, x, Wp, deg, rows,
                  abf, wbf, N_NODES);
        return;
    }
    const int t = threadIdx.x;

    // exclusive scan of bsum[782]: 4 contiguous values/thread + one 256-scan
    const int i0 = t * 4;
    int a0 = (i0 + 0 < SCAN_NB) ? bsum[i0 + 0] : 0;
    int a1 = (i0 + 1 < SCAN_NB) ? bsum[i0 + 1] : 0;
    int a2 = (i0 + 2 < SCAN_NB) ? bsum[i0 + 2] : 0;
    int a3 = (i0 + 3 < SCAN_NB) ? bsum[i0 + 3] : 0;
    int s = a0 + a1 + a2 + a3;
    cur[t] = s;
    __syncthreads();
    #pragma unroll
    for (int d = 1; d < 256; d <<= 1) {
        int u = (t >= d) ? cur[t - d] : 0;
        __syncthreads();
        cur[t] += u;
        __syncthreads();
    }
    int excl = cur[t] - s;
    sb[i0 + 0] = excl;
    sb[i0 + 1] = excl + a0;
    sb[i0 + 2] = excl + a0 + a1;
    sb[i0 + 3] = excl + a0 + a1 + a2;
    __syncthreads();

    const int chunk = blockIdx.x >> 2;
    const int range = blockIdx.x & 3;
    const int nbase = range * RNODES;
    const unsigned char* bp = hist_part + (long)chunk * N_NODES + nbase;
    const int* op = off + nbase;
    for (int i = t; i < RNODES; i += 256) {
        int c = op[i] + sb[(nbase + i) >> 6] + (int)bp[i];
        cur[i] = c;
        if (chunk == 0)                       // bp==0 here: c = absolute row beg
            rowinfo[nbase + i] = make_int2(c, deg[nbase + i]);
    }
    __syncthreads();
    const int* dp = dst + chunk * CEDGES;
    const int* sp = src + chunk * CEDGES;
    for (int i = t; i < CEDGES; i += 256) {
        int d = dp[i] - nbase;
        if ((unsigned)d < (unsigned)RNODES) {
            int pos = atomicAdd(&cur[d], 1);
            csr[pos] = sp[i];
        }
    }
}

// ---------------------------------------------------------------------------
// CSR gather + output: one wave per node; lane = (edge group g, feature
// quad f); 512 B per load instr; 16-edge main iteration = 4 independent
// load pairs in flight; xor-shuffle reduce; out = relu(S' + w).
__global__ __launch_bounds__(256) void gather_out_kernel(
    const int2* __restrict__ rowinfo, const int* __restrict__ csr,
    const unsigned short* __restrict__ abf,
    const unsigned short* __restrict__ wbf,
    float* __restrict__ out_f, unsigned short* __restrict__ out_b, int last)
{
    int node = blockIdx.x * 4 + (threadIdx.x >> 6);
    int lane = threadIdx.x & 63;
    const int g = lane >> 4;
    const int f = (lane & 15) * 4;
    int2 ri = rowinfo[node];
    int beg = ri.x;
    int end = beg + ri.y;
    float ax = 0.f, ay = 0.f, az = 0.f, aw = 0.f;
    int j = beg;
    for (; j + 16 <= end; j += 16) {
        int s0 = csr[j + g], s1 = csr[j + 4 + g];
        int s2 = csr[j + 8 + g], s3 = csr[j + 12 + g];
        ushort4 v0 = *(const ushort4*)(abf + (long)s0 * 64 + f);
        ushort4 v1 = *(const ushort4*)(abf + (long)s1 * 64 + f);
        ushort4 v2 = *(const ushort4*)(abf + (long)s2 * 64 + f);
        ushort4 v3 = *(const ushort4*)(abf + (long)s3 * 64 + f);
        ax += b2f(v0.x) + b2f(v1.x) + b2f(v2.x) + b2f(v3.x);
        ay += b2f(v0.y) + b2f(v1.y) + b2f(v2.y) + b2f(v3.y);
        az += b2f(v0.z) + b2f(v1.z) + b2f(v2.z) + b2f(v3.z);
        aw += b2f(v0.w) + b2f(v1.w) + b2f(v2.w) + b2f(v3.w);
    }
    for (; j + 8 <= end; j += 8) {
        int s0 = csr[j + g], s1 = csr[j + 4 + g];
        ushort4 v0 = *(const ushort4*)(abf + (long)s0 * 64 + f);
        ushort4 v1 = *(const ushort4*)(abf + (long)s1 * 64 + f);
        ax += b2f(v0.x) + b2f(v1.x);
        ay += b2f(v0.y) + b2f(v1.y);
        az += b2f(v0.z) + b2f(v1.z);
        aw += b2f(v0.w) + b2f(v1.w);
    }
    for (; j < end; j += 4) {
        int jj = j + g;
        if (jj < end) {
            int s0 = csr[jj];
            ushort4 v0 = *(const ushort4*)(abf + (long)s0 * 64 + f);
            ax += b2f(v0.x); ay += b2f(v0.y); az += b2f(v0.z); aw += b2f(v0.w);
        }
    }
    #pragma unroll
    for (int m = 16; m < 64; m <<= 1) {
        ax += __shfl_xor(ax, m, 64);
        ay += __shfl_xor(ay, m, 64);
        az += __shfl_xor(az, m, 64);
        aw += __shfl_xor(aw, m, 64);
    }
    if (g == 0) {
        ushort4 wv = *(const ushort4*)(wbf + (long)node * 64 + f);
        float o0 = fmaxf(ax + b2f(wv.x), 0.f);
        float o1 = fmaxf(ay + b2f(wv.y), 0.f);
        float o2 = fmaxf(az + b2f(wv.z), 0.f);
        float o3 = fmaxf(aw + b2f(wv.w), 0.f);
        if (last) {
            float4 o = {o0, o1, o2, o3};
            *(float4*)(out_f + (long)node * 64 + f) = o;
        } else {
            ushort4 o;
            o.x = f2b(o0); o.y = f2b(o1); o.z = f2b(o2); o.w = f2b(o3);
            *(ushort4*)(out_b + (long)node * 64 + f) = o;
        }
    }
}

// ---------------------------------------------------------------------------
extern "C" void kernel_launch(void* const* d_in, const int* in_sizes, int n_in,
                              void* d_out, int out_size, void* d_ws, size_t ws_size,
                              hipStream_t stream) {
    const float* x  = (const float*)d_in[0];
    const int*   ei = (const int*)d_in[1];
    const int*   src = ei;
    const int*   dst = ei + N_EDGES;

    char* wsb = (char*)d_ws;
    unsigned char*  hist_part = (unsigned char*)(wsb);          // 6.4 MB (u8)
    unsigned short* abf  = (unsigned short*)(wsb + 12800000);   // 6.4 MB
    unsigned short* wbf  = (unsigned short*)(wsb + 19200000);   // 6.4 MB
    unsigned short* h1   = (unsigned short*)(wsb + 25600000);   // 6.4 MB
    unsigned short* Wp   = (unsigned short*)(wsb + 38400000);   // 72 KB
    float*          rows = (float*)(wsb + 38500000);            // 1.5 KB
    int*  off     = (int*)(wsb + 38600000);                     // N_NODES
    int*  deg     = (int*)(wsb + 38900000);                     // N_NODES
    int*  bsum    = (int*)(wsb + 39200000);                     // 1024
    int2* rowinfo = (int2*)(wsb + 39300000);                    // N_NODES int2
    int*  csr     = (int*)(wsb + 39800000);                     // N_EDGES

    AllPtrs ap;
    for (int l = 0; l < 3; ++l) {
        int base = 2 + l * 7;
        ap.l[l].W1 = (const float*)d_in[base + 0];
        ap.l[l].b1 = (const float*)d_in[base + 1];
        ap.l[l].W2 = (const float*)d_in[base + 2];
        ap.l[l].W3 = (const float*)d_in[base + 3];
        ap.l[l].b3 = (const float*)d_in[base + 4];
        ap.l[l].Wl = (const float*)d_in[base + 5];
        ap.l[l].bl = (const float*)d_in[base + 6];
    }

    // ---- CSR build + weight pack; layer-0 GEMM overlaps the fill ----
    histpack_kernel<<<HIST_NB + 36, 256, 0, stream>>>(dst, hist_part, ap, Wp, rows);
    scanA2_kernel<<<SCAN_NB, 256, 0, stream>>>(hist_part, off, deg, bsum);
    fillgemm_kernel<<<HIST_NB + NBLK, 256, 0, stream>>>(
        src, dst, off, bsum, hist_part, csr, rowinfo,
        x, Wp, deg, rows, abf, wbf);

    // layer 0 gather (gemm0 already done inside fillgemm)
    gather_out_kernel<<<N_NODES / 4, 256, 0, stream>>>(
        rowinfo, csr, abf, wbf, (float*)d_out, h1, 0);

    const unsigned short* hin = h1;
    for (int l = 1; l < 3; ++l) {
        gemm3w_kernel<<<NBLK, 256, 0, stream>>>(
            hin, nullptr, Wp + l * 12288, deg, rows + l * 128,
            abf, wbf, N_NODES);
        gather_out_kernel<<<N_NODES / 4, 256, 0, stream>>>(
            rowinfo, csr, abf, wbf, (float*)d_out, h1, (l == 2));
        hin = h1;
    }
}

// Round 7
// 264.902 us; speedup vs baseline: 1.3287x; 1.0152x over previous
//
#include <hip/hip_runtime.h>

#define N_NODES 50000
#define N_EDGES 800000
#define NCHUNK 128
#define NRANGE 4
#define RNODES (N_NODES / NRANGE)         // 12500
#define CEDGES (N_EDGES / NCHUNK)         // 6250
#define HIST_NB (NCHUNK * NRANGE)         // 512
#define SCAN_NB 782                       // 64-node scan blocks
#define NBLK 782                          // 64-row GEMM tiles
#define FUSE_NB (N_NODES / 16)            // 3125 fused gather blocks

typedef __attribute__((ext_vector_type(8))) short short8;
typedef __attribute__((ext_vector_type(4))) float f32x4;

struct LPtrs { const float *W1, *W2, *W3, *Wl, *b1, *b3, *bl; };
struct AllPtrs { LPtrs l[3]; };

__device__ inline unsigned short f2b(float f) {
    union { float f; unsigned u; } c; c.f = f;
    return (unsigned short)((c.u + 0x7FFFu + ((c.u >> 16) & 1u)) >> 16);
}
__device__ inline float b2f(unsigned short h) {
    union { unsigned u; float f; } c; c.u = ((unsigned)h) << 16;
    return c.f;
}

// ---------------------------------------------------------------------------
// K1 (fused): blocks 0..511 partial histograms (packed-u8 LDS atomics);
// blocks 512..547 pack Wml = Wm@Wl into B-frag bf16 + bias rows.
__global__ __launch_bounds__(256) void histpack_kernel(const int* __restrict__ dst,
                                                       unsigned char* __restrict__ hist_part,
                                                       AllPtrs ap,
                                                       unsigned short* __restrict__ Wp,
                                                       float* __restrict__ rows) {
    __shared__ unsigned int h[5248];          // 21 KB
    const int t = threadIdx.x;
    if (blockIdx.x < HIST_NB) {
        const int chunk = blockIdx.x >> 2;
        const int range = blockIdx.x & 3;
        const int nbase = range * RNODES;
        for (int i = t; i < RNODES / 4; i += 256) h[i] = 0u;
        __syncthreads();
        const int* dp = dst + chunk * CEDGES;
        for (int i = t; i < CEDGES; i += 256) {
            int d = dp[i] - nbase;
            if ((unsigned)d < (unsigned)RNODES)
                atomicAdd(&h[d >> 2], 1u << ((d & 3) * 8));
        }
        __syncthreads();
        unsigned int* out = (unsigned int*)(hist_part + (long)chunk * N_NODES + nbase);
        for (int i = t; i < RNODES / 4; i += 256) out[i] = h[i];
    } else {
        float* sW = (float*)h;                // 64x65
        float* sL = (float*)h + 64 * 65;      // 64x17
        const int wi = blockIdx.x - HIST_NB;
        const int layer = wi / 12;
        const int ct = wi % 12;
        LPtrs L = ap.l[layer];
        const float* Wm = (ct < 4) ? L.W1 : (ct < 8) ? L.W2 : L.W3;
        const int colb = (ct & 3) * 16;
        for (int i = t; i < 64 * 64; i += 256) sW[(i >> 6) * 65 + (i & 63)] = Wm[i];
        for (int i = t; i < 64 * 16; i += 256) {
            int q = i >> 4, c = i & 15;
            sL[q * 17 + c] = L.Wl[q * 64 + colb + c];
        }
        __syncthreads();
        for (int local = t; local < 1024; local += 256) {
            int j = local & 7, lane = (local >> 3) & 63, s = local >> 9;
            int k = s * 32 + (lane >> 4) * 8 + j;
            int c = lane & 15;
            float acc = 0.f;
            #pragma unroll 8
            for (int q = 0; q < 64; ++q) acc += sW[k * 65 + q] * sL[q * 17 + c];
            Wp[layer * 12288 + ct * 1024 + local] = f2b(acc);
        }
        if (ct == 0 && t < 64) {
            int col = t;
            float r1 = 0.f, r3 = 0.f;
            for (int q = 0; q < 64; ++q) {
                float wl = L.Wl[q * 64 + col];
                r1 += L.b1[q] * wl;
                r3 += L.b3[q] * wl;
            }
            rows[layer * 128 + col] = r1;
            rows[layer * 128 + 64 + col] = r3 + L.bl[col];
        }
    }
}

// ---------------------------------------------------------------------------
// K2: per-node exclusive scan across 128 chunks, 4 threads/node (32
// independent u8 loads each). 64 nodes/block, 782 blocks.
__global__ __launch_bounds__(256) void scanA2_kernel(unsigned char* __restrict__ hist_part,
                                                     int* __restrict__ off,
                                                     int* __restrict__ deg,
                                                     int* __restrict__ bsum) {
    __shared__ int part[4][64];
    const int t = threadIdx.x;
    const int ln = t & 63;
    const int cg = t >> 6;
    const int node = blockIdx.x * 64 + ln;
    unsigned char* col = hist_part + node;
    unsigned char v[32];
    int s = 0;
    if (node < N_NODES) {
        #pragma unroll
        for (int k = 0; k < 32; ++k) {
            v[k] = col[(long)(cg * 32 + k) * N_NODES];
            s += v[k];
        }
    }
    part[cg][ln] = s;
    __syncthreads();
    int run = 0, tot = 0;
    #pragma unroll
    for (int g = 0; g < 4; ++g) {
        int p = part[g][ln];
        if (g < cg) run += p;
        tot += p;
    }
    if (node < N_NODES) {
        #pragma unroll
        for (int k = 0; k < 32; ++k) {
            col[(long)(cg * 32 + k) * N_NODES] = (unsigned char)run;
            run += v[k];
        }
    }
    if (cg == 0) {
        if (node < N_NODES) deg[node] = tot;
        int x = tot;
        #pragma unroll
        for (int d = 1; d < 64; d <<= 1) {
            int u = __shfl_up(x, d, 64);
            if (ln >= d) x += u;
        }
        if (node < N_NODES) off[node] = x - tot;
        if (ln == 63) bsum[blockIdx.x] = x;
    }
}

// ---------------------------------------------------------------------------
// K3: fill csr (bsum scan folded in; chunk-0 blocks publish rowinfo =
// {abs beg, deg}). Pure fill — no grid fusion (R6 lesson: fused gemm blocks
// inherit the 54 KB LDS allocation and lose all occupancy).
__global__ __launch_bounds__(256) void fillp_kernel(
    const int* __restrict__ src, const int* __restrict__ dst,
    const int* __restrict__ off, const int* __restrict__ bsum,
    const unsigned char* __restrict__ hist_part,
    int* __restrict__ csr, int2* __restrict__ rowinfo,
    const int* __restrict__ deg)
{
    __shared__ int cur[RNODES];               // 50 KB (scan reuses first 256)
    __shared__ int sb[1024];
    const int t = threadIdx.x;

    const int i0 = t * 4;
    int a0 = (i0 + 0 < SCAN_NB) ? bsum[i0 + 0] : 0;
    int a1 = (i0 + 1 < SCAN_NB) ? bsum[i0 + 1] : 0;
    int a2 = (i0 + 2 < SCAN_NB) ? bsum[i0 + 2] : 0;
    int a3 = (i0 + 3 < SCAN_NB) ? bsum[i0 + 3] : 0;
    int s = a0 + a1 + a2 + a3;
    cur[t] = s;
    __syncthreads();
    #pragma unroll
    for (int d = 1; d < 256; d <<= 1) {
        int u = (t >= d) ? cur[t - d] : 0;
        __syncthreads();
        cur[t] += u;
        __syncthreads();
    }
    int excl = cur[t] - s;
    sb[i0 + 0] = excl;
    sb[i0 + 1] = excl + a0;
    sb[i0 + 2] = excl + a0 + a1;
    sb[i0 + 3] = excl + a0 + a1 + a2;
    __syncthreads();

    const int chunk = blockIdx.x >> 2;
    const int range = blockIdx.x & 3;
    const int nbase = range * RNODES;
    const unsigned char* bp = hist_part + (long)chunk * N_NODES + nbase;
    const int* op = off + nbase;
    for (int i = t; i < RNODES; i += 256) {
        int c = op[i] + sb[(nbase + i) >> 6] + (int)bp[i];
        cur[i] = c;
        if (chunk == 0)                       // bp==0 here: c = absolute row beg
            rowinfo[nbase + i] = make_int2(c, deg[nbase + i]);
    }
    __syncthreads();
    const int* dp = dst + chunk * CEDGES;
    const int* sp = src + chunk * CEDGES;
    for (int i = t; i < CEDGES; i += 256) {
        int d = dp[i] - nbase;
        if ((unsigned)d < (unsigned)RNODES) {
            int pos = atomicAdd(&cur[d], 1);
            csr[pos] = sp[i];
        }
    }
}

// ---------------------------------------------------------------------------
// K4: layer-0 GEMM (reads fp32 x): a' = x@W1l; w = x@W3l - deg*(x@W2l-r1)+r3.
__global__ __launch_bounds__(256) void gemm3w_kernel(
    const float* __restrict__ hf32, const unsigned short* __restrict__ Wp,
    const int* __restrict__ deg, const float* __restrict__ rows,
    unsigned short* __restrict__ abf, unsigned short* __restrict__ wbf)
{
    const int t = threadIdx.x;
    const int lane = t & 63;
    const int quad = lane >> 4, lm = lane & 15;
    const int row_base = blockIdx.x * 64 + (t >> 6) * 16;

    int arow = min(row_base + lm, N_NODES - 1);
    short8 a0, a1;
    const float* hrow = hf32 + (long)arow * 64;
    #pragma unroll
    for (int j = 0; j < 8; ++j) {
        a0[j] = (short)f2b(hrow[quad * 8 + j]);
        a1[j] = (short)f2b(hrow[32 + quad * 8 + j]);
    }

    const short8* wp = (const short8*)Wp;
    f32x4 acc[12];
    #pragma unroll
    for (int ct = 0; ct < 12; ++ct) {
        f32x4 z = {0.f, 0.f, 0.f, 0.f};
        short8 w0 = wp[(ct * 2 + 0) * 64 + lane];
        short8 w1 = wp[(ct * 2 + 1) * 64 + lane];
        z = __builtin_amdgcn_mfma_f32_16x16x32_bf16(a0, w0, z, 0, 0, 0);
        z = __builtin_amdgcn_mfma_f32_16x16x32_bf16(a1, w1, z, 0, 0, 0);
        acc[ct] = z;
    }

    const int g0 = row_base + quad * 4;
    float dg[4];
    #pragma unroll
    for (int r = 0; r < 4; ++r) dg[r] = (float)deg[min(g0 + r, N_NODES - 1)];

    #pragma unroll
    for (int ct = 0; ct < 4; ++ct) {
        int col = ct * 16 + lm;
        float r1 = rows[col];
        float r3 = rows[64 + col];
        #pragma unroll
        for (int r = 0; r < 4; ++r) {
            int g = g0 + r;
            if (g < N_NODES) {
                abf[(long)g * 64 + col] = f2b(acc[ct][r]);
                float wv = acc[8 + ct][r] - dg[r] * (acc[4 + ct][r] - r1) + r3;
                wbf[(long)g * 64 + col] = f2b(wv);
            }
        }
    }
}

// ---------------------------------------------------------------------------
// K5 (the new fusion): block = 16 nodes. Phase 1: each of 4 waves gathers 4
// nodes (S' = sum a'_in rows; h = relu(S'+w_in)) into a 2.3 KB LDS tile.
// Phase 2 (after one sync): each wave computes its 16-col slice of the NEXT
// layer's GEMM (a'_out, w_out) from the tile — removes the standalone gemm
// dispatch + h round-trip. Ping-pong a/w buffers (no intra-dispatch races).
__global__ __launch_bounds__(256) void gatherfuse_kernel(
    const int2* __restrict__ rowinfo, const int* __restrict__ csr,
    const unsigned short* __restrict__ abf_in,
    const unsigned short* __restrict__ wbf_in,
    const unsigned short* __restrict__ Wp,     // next-layer tiles
    const int* __restrict__ deg, const float* __restrict__ rows, // next-layer
    unsigned short* __restrict__ abf_out, unsigned short* __restrict__ wbf_out)
{
    __shared__ unsigned short htile[16][72];   // 16-row tile, 144B row stride
    const int t = threadIdx.x;
    const int wv = t >> 6;
    const int lane = t & 63;
    const int g = lane >> 4;
    const int f = (lane & 15) * 4;
    const int nbase = blockIdx.x * 16;

    #pragma unroll
    for (int k = 0; k < 4; ++k) {
        const int nl = wv * 4 + k;
        const int node = nbase + nl;
        int2 ri = rowinfo[node];
        int beg = ri.x;
        int end = beg + ri.y;
        float ax = 0.f, ay = 0.f, az = 0.f, aw = 0.f;
        int j = beg;
        for (; j + 16 <= end; j += 16) {
            int s0 = csr[j + g], s1 = csr[j + 4 + g];
            int s2 = csr[j + 8 + g], s3 = csr[j + 12 + g];
            ushort4 v0 = *(const ushort4*)(abf_in + (long)s0 * 64 + f);
            ushort4 v1 = *(const ushort4*)(abf_in + (long)s1 * 64 + f);
            ushort4 v2 = *(const ushort4*)(abf_in + (long)s2 * 64 + f);
            ushort4 v3 = *(const ushort4*)(abf_in + (long)s3 * 64 + f);
            ax += b2f(v0.x) + b2f(v1.x) + b2f(v2.x) + b2f(v3.x);
            ay += b2f(v0.y) + b2f(v1.y) + b2f(v2.y) + b2f(v3.y);
            az += b2f(v0.z) + b2f(v1.z) + b2f(v2.z) + b2f(v3.z);
            aw += b2f(v0.w) + b2f(v1.w) + b2f(v2.w) + b2f(v3.w);
        }
        for (; j + 8 <= end; j += 8) {
            int s0 = csr[j + g], s1 = csr[j + 4 + g];
            ushort4 v0 = *(const ushort4*)(abf_in + (long)s0 * 64 + f);
            ushort4 v1 = *(const ushort4*)(abf_in + (long)s1 * 64 + f);
            ax += b2f(v0.x) + b2f(v1.x);
            ay += b2f(v0.y) + b2f(v1.y);
            az += b2f(v0.z) + b2f(v1.z);
            aw += b2f(v0.w) + b2f(v1.w);
        }
        for (; j < end; j += 4) {
            int jj = j + g;
            if (jj < end) {
                int s0 = csr[jj];
                ushort4 v0 = *(const ushort4*)(abf_in + (long)s0 * 64 + f);
                ax += b2f(v0.x); ay += b2f(v0.y); az += b2f(v0.z); aw += b2f(v0.w);
            }
        }
        #pragma unroll
        for (int m = 16; m < 64; m <<= 1) {
            ax += __shfl_xor(ax, m, 64);
            ay += __shfl_xor(ay, m, 64);
            az += __shfl_xor(az, m, 64);
            aw += __shfl_xor(aw, m, 64);
        }
        if (g == 0) {
            ushort4 wvv = *(const ushort4*)(wbf_in + (long)node * 64 + f);
            ushort4 o;
            o.x = f2b(fmaxf(ax + b2f(wvv.x), 0.f));
            o.y = f2b(fmaxf(ay + b2f(wvv.y), 0.f));
            o.z = f2b(fmaxf(az + b2f(wvv.z), 0.f));
            o.w = f2b(fmaxf(aw + b2f(wvv.w), 0.f));
            *(ushort4*)(&htile[nl][f]) = o;
        }
    }
    __syncthreads();

    // GEMM phase: wave wv owns column slice [wv*16, wv*16+16).
    const int quad = lane >> 4, lm = lane & 15;
    short8 a0 = *(const short8*)(&htile[lm][quad * 8]);
    short8 a1 = *(const short8*)(&htile[lm][32 + quad * 8]);

    const short8* wp = (const short8*)Wp;
    f32x4 za = {0.f, 0.f, 0.f, 0.f};
    f32x4 z2 = {0.f, 0.f, 0.f, 0.f};
    f32x4 z3 = {0.f, 0.f, 0.f, 0.f};
    {
        int t1 = wv, t2 = 4 + wv, t3 = 8 + wv;
        za = __builtin_amdgcn_mfma_f32_16x16x32_bf16(a0, wp[(t1 * 2 + 0) * 64 + lane], za, 0, 0, 0);
        za = __builtin_amdgcn_mfma_f32_16x16x32_bf16(a1, wp[(t1 * 2 + 1) * 64 + lane], za, 0, 0, 0);
        z2 = __builtin_amdgcn_mfma_f32_16x16x32_bf16(a0, wp[(t2 * 2 + 0) * 64 + lane], z2, 0, 0, 0);
        z2 = __builtin_amdgcn_mfma_f32_16x16x32_bf16(a1, wp[(t2 * 2 + 1) * 64 + lane], z2, 0, 0, 0);
        z3 = __builtin_amdgcn_mfma_f32_16x16x32_bf16(a0, wp[(t3 * 2 + 0) * 64 + lane], z3, 0, 0, 0);
        z3 = __builtin_amdgcn_mfma_f32_16x16x32_bf16(a1, wp[(t3 * 2 + 1) * 64 + lane], z3, 0, 0, 0);
    }

    const int col = wv * 16 + lm;
    const float r1 = rows[col];
    const float r3 = rows[64 + col];
    #pragma unroll
    for (int r = 0; r < 4; ++r) {
        int grow = nbase + quad * 4 + r;
        float dg = (float)deg[grow];
        abf_out[(long)grow * 64 + col] = f2b(za[r]);
        float wvl = z3[r] - dg * (z2[r] - r1) + r3;
        wbf_out[(long)grow * 64 + col] = f2b(wvl);
    }
}

// ---------------------------------------------------------------------------
// K6: final-layer gather + f32 output (no next layer to feed).
__global__ __launch_bounds__(256) void gather_out_kernel(
    const int2* __restrict__ rowinfo, const int* __restrict__ csr,
    const unsigned short* __restrict__ abf,
    const unsigned short* __restrict__ wbf,
    float* __restrict__ out_f)
{
    int node = blockIdx.x * 4 + (threadIdx.x >> 6);
    int lane = threadIdx.x & 63;
    const int g = lane >> 4;
    const int f = (lane & 15) * 4;
    int2 ri = rowinfo[node];
    int beg = ri.x;
    int end = beg + ri.y;
    float ax = 0.f, ay = 0.f, az = 0.f, aw = 0.f;
    int j = beg;
    for (; j + 16 <= end; j += 16) {
        int s0 = csr[j + g], s1 = csr[j + 4 + g];
        int s2 = csr[j + 8 + g], s3 = csr[j + 12 + g];
        ushort4 v0 = *(const ushort4*)(abf + (long)s0 * 64 + f);
        ushort4 v1 = *(const ushort4*)(abf + (long)s1 * 64 + f);
        ushort4 v2 = *(const ushort4*)(abf + (long)s2 * 64 + f);
        ushort4 v3 = *(const ushort4*)(abf + (long)s3 * 64 + f);
        ax += b2f(v0.x) + b2f(v1.x) + b2f(v2.x) + b2f(v3.x);
        ay += b2f(v0.y) + b2f(v1.y) + b2f(v2.y) + b2f(v3.y);
        az += b2f(v0.z) + b2f(v1.z) + b2f(v2.z) + b2f(v3.z);
        aw += b2f(v0.w) + b2f(v1.w) + b2f(v2.w) + b2f(v3.w);
    }
    for (; j + 8 <= end; j += 8) {
        int s0 = csr[j + g], s1 = csr[j + 4 + g];
        ushort4 v0 = *(const ushort4*)(abf + (long)s0 * 64 + f);
        ushort4 v1 = *(const ushort4*)(abf + (long)s1 * 64 + f);
        ax += b2f(v0.x) + b2f(v1.x);
        ay += b2f(v0.y) + b2f(v1.y);
        az += b2f(v0.z) + b2f(v1.z);
        aw += b2f(v0.w) + b2f(v1.w);
    }
    for (; j < end; j += 4) {
        int jj = j + g;
        if (jj < end) {
            int s0 = csr[jj];
            ushort4 v0 = *(const ushort4*)(abf + (long)s0 * 64 + f);
            ax += b2f(v0.x); ay += b2f(v0.y); az += b2f(v0.z); aw += b2f(v0.w);
        }
    }
    #pragma unroll
    for (int m = 16; m < 64; m <<= 1) {
        ax += __shfl_xor(ax, m, 64);
        ay += __shfl_xor(ay, m, 64);
        az += __shfl_xor(az, m, 64);
        aw += __shfl_xor(aw, m, 64);
    }
    if (g == 0) {
        ushort4 wv = *(const ushort4*)(wbf + (long)node * 64 + f);
        float4 o;
        o.x = fmaxf(ax + b2f(wv.x), 0.f);
        o.y = fmaxf(ay + b2f(wv.y), 0.f);
        o.z = fmaxf(az + b2f(wv.z), 0.f);
        o.w = fmaxf(aw + b2f(wv.w), 0.f);
        *(float4*)(out_f + (long)node * 64 + f) = o;
    }
}

// ---------------------------------------------------------------------------
extern "C" void kernel_launch(void* const* d_in, const int* in_sizes, int n_in,
                              void* d_out, int out_size, void* d_ws, size_t ws_size,
                              hipStream_t stream) {
    const float* x  = (const float*)d_in[0];
    const int*   ei = (const int*)d_in[1];
    const int*   src = ei;
    const int*   dst = ei + N_EDGES;

    char* wsb = (char*)d_ws;
    unsigned char*  hist_part = (unsigned char*)(wsb);          // 6.4 MB (u8)
    unsigned short* abfA = (unsigned short*)(wsb + 6500000);    // 6.4 MB
    unsigned short* wbfA = (unsigned short*)(wsb + 12900000);   // 6.4 MB
    unsigned short* abfB = (unsigned short*)(wsb + 19300000);   // 6.4 MB
    unsigned short* wbfB = (unsigned short*)(wsb + 25700000);   // 6.4 MB
    unsigned short* Wp   = (unsigned short*)(wsb + 32100000);   // 72 KB
    float*          rows = (float*)(wsb + 32200000);            // 1.5 KB
    int*  off     = (int*)(wsb + 32300000);                     // N_NODES
    int*  deg     = (int*)(wsb + 32600000);                     // N_NODES
    int*  bsum    = (int*)(wsb + 32900000);                     // 1024
    int2* rowinfo = (int2*)(wsb + 33000000);                    // N_NODES int2
    int*  csr     = (int*)(wsb + 33500000);                     // N_EDGES

    AllPtrs ap;
    for (int l = 0; l < 3; ++l) {
        int base = 2 + l * 7;
        ap.l[l].W1 = (const float*)d_in[base + 0];
        ap.l[l].b1 = (const float*)d_in[base + 1];
        ap.l[l].W2 = (const float*)d_in[base + 2];
        ap.l[l].W3 = (const float*)d_in[base + 3];
        ap.l[l].b3 = (const float*)d_in[base + 4];
        ap.l[l].Wl = (const float*)d_in[base + 5];
        ap.l[l].bl = (const float*)d_in[base + 6];
    }

    // ---- CSR build + weight pack (R0-proven serial shape) ----
    histpack_kernel<<<HIST_NB + 36, 256, 0, stream>>>(dst, hist_part, ap, Wp, rows);
    scanA2_kernel<<<SCAN_NB, 256, 0, stream>>>(hist_part, off, deg, bsum);
    fillp_kernel<<<HIST_NB, 256, 0, stream>>>(src, dst, off, bsum, hist_part,
                                              csr, rowinfo, deg);

    // layer-0 GEMM (fp32 x -> a'/w into A)
    gemm3w_kernel<<<NBLK, 256, 0, stream>>>(x, Wp, deg, rows, abfA, wbfA);

    // layer 0 gather + fused layer-1 GEMM: A -> B
    gatherfuse_kernel<<<FUSE_NB, 256, 0, stream>>>(
        rowinfo, csr, abfA, wbfA, Wp + 12288, deg, rows + 128, abfB, wbfB);

    // layer 1 gather + fused layer-2 GEMM: B -> A
    gatherfuse_kernel<<<FUSE_NB, 256, 0, stream>>>(
        rowinfo, csr, abfB, wbfB, Wp + 24576, deg, rows + 256, abfA, wbfA);

    // layer 2 gather + f32 output
    gather_out_kernel<<<N_NODES / 4, 256, 0, stream>>>(
        rowinfo, csr, abfA, wbfA, (float*)d_out);
}